// Round 1
// baseline (605.656 us; speedup 1.0000x reference)
//
#include <hip/hip_runtime.h>
#include <math.h>

#define BATCH 128
#define NCI 768
#define NCO 64
#define DIN 8
#define DOUT 16

// ---------------- conv1: x(128,3,32,42) w(32,3,6,6) stride 3 -> h1(128,32,9,13), relu
__global__ __launch_bounds__(256) void conv1_kernel(
    const float* __restrict__ x, const float* __restrict__ w,
    const float* __restrict__ bias, float* __restrict__ h1) {
    __shared__ float wl[32 * 3 * 36];  // 3456 floats
    for (int i = threadIdx.x; i < 3456; i += 256) wl[i] = w[i];
    __syncthreads();
    int idx = blockIdx.x * 256 + threadIdx.x;
    const int total = BATCH * 32 * 9 * 13;
    if (idx >= total) return;
    int ow = idx % 13; int t = idx / 13;
    int oh = t % 9; t /= 9;
    int oc = t % 32; int b = t / 32;
    float acc = bias[oc];
    const float* xb = x + (size_t)b * 3 * 32 * 42;
    #pragma unroll
    for (int ic = 0; ic < 3; ++ic) {
        const float* xc = xb + ic * 32 * 42 + (oh * 3) * 42 + ow * 3;
        const float* wc = wl + (oc * 3 + ic) * 36;
        #pragma unroll
        for (int kh = 0; kh < 6; ++kh)
            #pragma unroll
            for (int kw = 0; kw < 6; ++kw)
                acc += xc[kh * 42 + kw] * wc[kh * 6 + kw];
    }
    h1[idx] = fmaxf(acc, 0.f);
}

// ---------------- primary caps conv (k=3,s=2) + squash -> u_t[i][d][b]  (768*8*128)
// h2(b,c2,h,w) with H2=4,W2=6; capsule i = c2*3+g, elem d: spatial s=g*8+d, h=s/6, w=s%6
__global__ __launch_bounds__(192) void pc_kernel(
    const float* __restrict__ h1, const float* __restrict__ w,
    const float* __restrict__ bias, float* __restrict__ u_t) {
    __shared__ float hl[32 * 9 * 13];   // 3744 floats
    __shared__ float wl[8 * 32 * 9];    // 2304 floats
    int b = blockIdx.x, cg = blockIdx.y;  // cg: group of 8 channels
    const float* hb = h1 + (size_t)b * 3744;
    for (int i = threadIdx.x; i < 3744; i += 192) hl[i] = hb[i];
    const float* wg = w + (size_t)cg * 8 * 288;
    for (int i = threadIdx.x; i < 2304; i += 192) wl[i] = wg[i];
    __syncthreads();
    int s = threadIdx.x % 24;
    int c2l = threadIdx.x / 24;
    int h = s / 6, wc = s % 6;
    int c2 = cg * 8 + c2l;
    float acc = bias[c2];
    const float* wp0 = wl + c2l * 288;
    #pragma unroll 4
    for (int ic = 0; ic < 32; ++ic) {
        const float* hp = hl + ic * 117 + (h * 2) * 13 + wc * 2;
        const float* wp = wp0 + ic * 9;
        acc += hp[0] * wp[0] + hp[1] * wp[1] + hp[2] * wp[2]
             + hp[13] * wp[3] + hp[14] * wp[4] + hp[15] * wp[5]
             + hp[26] * wp[6] + hp[27] * wp[7] + hp[28] * wp[8];
    }
    // squash across the 8-thread capsule group (consecutive, 8-aligned)
    float n2 = acc * acc;
    n2 += __shfl_xor(n2, 1, 64);
    n2 += __shfl_xor(n2, 2, 64);
    n2 += __shfl_xor(n2, 4, 64);
    float n = sqrtf(n2);
    float val = acc * n / (1.f + n2);
    // u_t[(i*8+d)][b] ; i*8+d = c2*24 + s = cg*192 + tid
    u_t[((size_t)cg * 192 + threadIdx.x) * 128 + b] = val;
}

// ---------------- s-pass: s_part[it][b][o][k] = sum_{i in tile} c[b,i,o] * (W[i,o]@u[b,i])
// c_t layout [o][i][b]; u_t layout [i][d][b]
template <bool UNIFORM>
__global__ __launch_bounds__(128) void spass_kernel(
    const float* __restrict__ W, const float* __restrict__ u_t,
    const float* __restrict__ c_t, float* __restrict__ s_part) {
    int o = blockIdx.x;        // 0..63
    int it = blockIdx.y;       // 0..11
    int i0 = it * 64;
    __shared__ float wl[64 * 128];  // 32KB: wl[ii][k*8+d]
    const float* wsrc = W + (size_t)i0 * 8192 + (size_t)o * 128;
    for (int idx = threadIdx.x; idx < 2048; idx += 128) {
        int ii = idx >> 5, q = idx & 31;
        *(float4*)(wl + ii * 128 + q * 4) = *(const float4*)(wsrc + (size_t)ii * 8192 + q * 4);
    }
    __syncthreads();
    int b = threadIdx.x;
    float s[16];
    #pragma unroll
    for (int k = 0; k < 16; ++k) s[k] = 0.f;
    const float* ub = u_t + (size_t)i0 * 8 * 128 + b;
    const float* cb = c_t + ((size_t)o * 768 + i0) * 128 + b;
    for (int ii = 0; ii < 64; ++ii) {
        float c = UNIFORM ? 1.f : cb[ii * 128];
        float cu[8];
        #pragma unroll
        for (int d = 0; d < 8; ++d) cu[d] = c * ub[(ii * 8 + d) * 128];
        const float4* wr = (const float4*)(wl + ii * 128);
        #pragma unroll
        for (int k = 0; k < 16; ++k) {
            float4 w0 = wr[k * 2], w1 = wr[k * 2 + 1];
            s[k] += w0.x * cu[0] + w0.y * cu[1] + w0.z * cu[2] + w0.w * cu[3]
                  + w1.x * cu[4] + w1.y * cu[5] + w1.z * cu[6] + w1.w * cu[7];
        }
    }
    float* sp = s_part + (((size_t)it * 128 + b) * 64 + o) * 16;
    #pragma unroll
    for (int k = 0; k < 16; ++k) sp[k] = s[k];
}

// ---------------- reduce partials + squash -> v[b][o][k] (writes ws v or d_out)
__global__ __launch_bounds__(256) void squashv_kernel(
    const float* __restrict__ s_part, float* __restrict__ v, float scale) {
    int idx = blockIdx.x * 256 + threadIdx.x;  // b*1024 + o*16 + k
    float acc = 0.f;
    #pragma unroll
    for (int it = 0; it < 12; ++it) acc += s_part[(size_t)it * 131072 + idx];
    acc *= scale;
    float n2 = acc * acc;
    n2 += __shfl_xor(n2, 1, 64);
    n2 += __shfl_xor(n2, 2, 64);
    n2 += __shfl_xor(n2, 4, 64);
    n2 += __shfl_xor(n2, 8, 64);
    float n = sqrtf(n2);
    v[idx] = acc * n / (1.f + n2);
}

// ---------------- b-pass: blog[o][i][b] (+)= sum_k (W[i,o]@u[b,i])[k] * v[b,o,k]
template <bool ACCUM>
__global__ __launch_bounds__(128) void bpass_kernel(
    const float* __restrict__ W, const float* __restrict__ u_t,
    const float* __restrict__ v, float* __restrict__ blog) {
    int o = blockIdx.x, it = blockIdx.y, i0 = it * 64;
    __shared__ float wl[64 * 128];
    __shared__ float vl[128 * 16];
    const float* wsrc = W + (size_t)i0 * 8192 + (size_t)o * 128;
    for (int idx = threadIdx.x; idx < 2048; idx += 128) {
        int ii = idx >> 5, q = idx & 31;
        *(float4*)(wl + ii * 128 + q * 4) = *(const float4*)(wsrc + (size_t)ii * 8192 + q * 4);
    }
    for (int idx = threadIdx.x; idx < 512; idx += 128) {
        int bb = idx >> 2, q = idx & 3;
        *(float4*)(vl + bb * 16 + q * 4) = *(const float4*)(v + ((size_t)bb * 64 + o) * 16 + q * 4);
    }
    __syncthreads();
    int b = threadIdx.x;
    float vv[16];
    #pragma unroll
    for (int k = 0; k < 16; ++k) vv[k] = vl[b * 16 + k];
    const float* ub = u_t + (size_t)i0 * 8 * 128 + b;
    float* bl = blog + ((size_t)o * 768 + i0) * 128 + b;
    for (int ii = 0; ii < 64; ++ii) {
        float uu[8];
        #pragma unroll
        for (int d = 0; d < 8; ++d) uu[d] = ub[(ii * 8 + d) * 128];
        const float4* wr = (const float4*)(wl + ii * 128);
        float delta = 0.f;
        #pragma unroll
        for (int k = 0; k < 16; ++k) {
            float4 w0 = wr[k * 2], w1 = wr[k * 2 + 1];
            float wd = w0.x * uu[0] + w0.y * uu[1] + w0.z * uu[2] + w0.w * uu[3]
                     + w1.x * uu[4] + w1.y * uu[5] + w1.z * uu[6] + w1.w * uu[7];
            delta += vv[k] * wd;
        }
        if (ACCUM) bl[ii * 128] += delta;
        else bl[ii * 128] = delta;
    }
}

// ---------------- softmax over o: c_t[o][i][b] = softmax_o(blog[o][i][b])
__global__ __launch_bounds__(128) void softmax_kernel(
    const float* __restrict__ blog, float* __restrict__ c_t) {
    int i = blockIdx.x;   // 0..767
    int b = threadIdx.x;  // 0..127
    const float* src = blog + (size_t)i * 128 + b;
    float r[64];
    float m = -1e30f;
    #pragma unroll
    for (int o = 0; o < 64; ++o) {
        r[o] = src[(size_t)o * 98304];
        m = fmaxf(m, r[o]);
    }
    float sum = 0.f;
    #pragma unroll
    for (int o = 0; o < 64; ++o) {
        r[o] = __expf(r[o] - m);
        sum += r[o];
    }
    float inv = 1.f / sum;
    float* dst = c_t + (size_t)i * 128 + b;
    #pragma unroll
    for (int o = 0; o < 64; ++o) dst[(size_t)o * 98304] = r[o] * inv;
}

extern "C" void kernel_launch(void* const* d_in, const int* in_sizes, int n_in,
                              void* d_out, int out_size, void* d_ws, size_t ws_size,
                              hipStream_t stream) {
    const float* x  = (const float*)d_in[0];
    const float* w1 = (const float*)d_in[1];
    const float* b1 = (const float*)d_in[2];
    const float* wp = (const float*)d_in[3];
    const float* bp = (const float*)d_in[4];
    const float* W  = (const float*)d_in[5];
    float* out = (float*)d_out;
    float* ws = (float*)d_ws;

    float* u_t    = ws;                  // 786432
    float* c_t    = ws + 786432;         // 6291456
    float* blog   = ws + 7077888;        // 6291456
    float* v      = ws + 13369344;       // 131072
    float* h1     = ws + 13500416;       // 479232 (region reused by s_part)
    float* s_part = ws + 13500416;       // 1572864

    conv1_kernel<<<1872, 256, 0, stream>>>(x, w1, b1, h1);
    pc_kernel<<<dim3(128, 32), 192, 0, stream>>>(h1, wp, bp, u_t);

    // iteration 0: c uniform (1/64 folded into squash scale)
    spass_kernel<true><<<dim3(64, 12), 128, 0, stream>>>(W, u_t, nullptr, s_part);
    squashv_kernel<<<512, 256, 0, stream>>>(s_part, v, 1.f / 64.f);
    bpass_kernel<false><<<dim3(64, 12), 128, 0, stream>>>(W, u_t, v, blog);

    // iteration 1
    softmax_kernel<<<768, 128, 0, stream>>>(blog, c_t);
    spass_kernel<false><<<dim3(64, 12), 128, 0, stream>>>(W, u_t, c_t, s_part);
    squashv_kernel<<<512, 256, 0, stream>>>(s_part, v, 1.f);
    bpass_kernel<true><<<dim3(64, 12), 128, 0, stream>>>(W, u_t, v, blog);

    // final
    softmax_kernel<<<768, 128, 0, stream>>>(blog, c_t);
    spass_kernel<false><<<dim3(64, 12), 128, 0, stream>>>(W, u_t, c_t, s_part);
    squashv_kernel<<<512, 256, 0, stream>>>(s_part, out, 1.f);
}

// Round 2
// 506.961 us; speedup vs baseline: 1.1947x; 1.1947x over previous
//
#include <hip/hip_runtime.h>
#include <math.h>

#define BATCH 128
#define NCI 768
#define NCO 64
#define DIN 8
#define DOUT 16

// ---------------- conv1: x(128,3,32,42) w(32,3,6,6) stride 3 -> h1(128,32,9,13), relu
__global__ __launch_bounds__(256) void conv1_kernel(
    const float* __restrict__ x, const float* __restrict__ w,
    const float* __restrict__ bias, float* __restrict__ h1) {
    __shared__ float wl[32 * 3 * 36];  // 3456 floats
    for (int i = threadIdx.x; i < 3456; i += 256) wl[i] = w[i];
    __syncthreads();
    int idx = blockIdx.x * 256 + threadIdx.x;
    const int total = BATCH * 32 * 9 * 13;
    if (idx >= total) return;
    int ow = idx % 13; int t = idx / 13;
    int oh = t % 9; t /= 9;
    int oc = t % 32; int b = t / 32;
    float acc = bias[oc];
    const float* xb = x + (size_t)b * 3 * 32 * 42;
    #pragma unroll
    for (int ic = 0; ic < 3; ++ic) {
        const float* xc = xb + ic * 32 * 42 + (oh * 3) * 42 + ow * 3;
        const float* wc = wl + (oc * 3 + ic) * 36;
        #pragma unroll
        for (int kh = 0; kh < 6; ++kh)
            #pragma unroll
            for (int kw = 0; kw < 6; ++kw)
                acc += xc[kh * 42 + kw] * wc[kh * 6 + kw];
    }
    h1[idx] = fmaxf(acc, 0.f);
}

// ---------------- primary caps conv (k=3,s=2) + squash -> u_t[i][b][d]  (768*128*8)
__global__ __launch_bounds__(192) void pc_kernel(
    const float* __restrict__ h1, const float* __restrict__ w,
    const float* __restrict__ bias, float* __restrict__ u_t) {
    __shared__ float hl[32 * 9 * 13];   // 3744 floats
    __shared__ float wl[8 * 32 * 9];    // 2304 floats
    int b = blockIdx.x, cg = blockIdx.y;  // cg: group of 8 channels
    const float* hb = h1 + (size_t)b * 3744;
    for (int i = threadIdx.x; i < 3744; i += 192) hl[i] = hb[i];
    const float* wg = w + (size_t)cg * 8 * 288;
    for (int i = threadIdx.x; i < 2304; i += 192) wl[i] = wg[i];
    __syncthreads();
    int s = threadIdx.x % 24;
    int c2l = threadIdx.x / 24;
    int h = s / 6, wc = s % 6;
    int c2 = cg * 8 + c2l;
    float acc = bias[c2];
    const float* wp0 = wl + c2l * 288;
    #pragma unroll 4
    for (int ic = 0; ic < 32; ++ic) {
        const float* hp = hl + ic * 117 + (h * 2) * 13 + wc * 2;
        const float* wp = wp0 + ic * 9;
        acc += hp[0] * wp[0] + hp[1] * wp[1] + hp[2] * wp[2]
             + hp[13] * wp[3] + hp[14] * wp[4] + hp[15] * wp[5]
             + hp[26] * wp[6] + hp[27] * wp[7] + hp[28] * wp[8];
    }
    // squash across the 8-thread capsule group (consecutive, 8-aligned)
    float n2 = acc * acc;
    n2 += __shfl_xor(n2, 1, 64);
    n2 += __shfl_xor(n2, 2, 64);
    n2 += __shfl_xor(n2, 4, 64);
    float n = sqrtf(n2);
    float val = acc * n / (1.f + n2);
    // capsule index i = (cg*192 + tid)/8, element d = tid & 7
    int gi = cg * 192 + threadIdx.x;
    u_t[(size_t)(gi >> 3) * 1024 + b * 8 + (gi & 7)] = val;
}

// ---------------- s-pass: s_part[it][b][o][k] = sum_{i in tile} c[b,i,o] * (W[i,o]@u[b,i])
// W read via wave-uniform scalar loads; u_t layout [i][b][8]; c_t layout [o][i][b]
template <bool UNIFORM>
__global__ __launch_bounds__(256) void spass_kernel(
    const float* __restrict__ W, const float* __restrict__ u_t,
    const float* __restrict__ c_t, float* __restrict__ s_part) {
    int o = blockIdx.x;        // 0..63
    int it = blockIdx.y;       // 0..11
    int b = threadIdx.x & 127;
    int ty = threadIdx.x >> 7;
    int i0 = it * 64 + ty * 32;
    float s[16];
    #pragma unroll
    for (int k = 0; k < 16; ++k) s[k] = 0.f;
    const float* ub = u_t + (size_t)i0 * 1024 + b * 8;
    const float* cb = c_t + ((size_t)o * 768 + i0) * 128 + b;
    #pragma unroll 2
    for (int ii = 0; ii < 32; ++ii) {
        float4 u0 = *(const float4*)(ub + ii * 1024);
        float4 u1 = *(const float4*)(ub + ii * 1024 + 4);
        float c = UNIFORM ? 1.f : cb[ii * 128];
        float cu[8];
        cu[0] = c * u0.x; cu[1] = c * u0.y; cu[2] = c * u0.z; cu[3] = c * u0.w;
        cu[4] = c * u1.x; cu[5] = c * u1.y; cu[6] = c * u1.z; cu[7] = c * u1.w;
        int base = __builtin_amdgcn_readfirstlane((i0 + ii) * 8192 + o * 128);
        const float* wp = W + base;
        #pragma unroll
        for (int k = 0; k < 16; ++k) {
            s[k] += wp[k * 8 + 0] * cu[0] + wp[k * 8 + 1] * cu[1]
                  + wp[k * 8 + 2] * cu[2] + wp[k * 8 + 3] * cu[3]
                  + wp[k * 8 + 4] * cu[4] + wp[k * 8 + 5] * cu[5]
                  + wp[k * 8 + 6] * cu[6] + wp[k * 8 + 7] * cu[7];
        }
    }
    // combine the two 32-capsule halves through LDS
    __shared__ float red[128 * 16];
    if (ty) {
        #pragma unroll
        for (int k = 0; k < 16; ++k) red[b * 16 + k] = s[k];
    }
    __syncthreads();
    if (!ty) {
        float* sp = s_part + (((size_t)it * 128 + b) * 64 + o) * 16;
        #pragma unroll
        for (int k = 0; k < 16; ++k) sp[k] = s[k] + red[b * 16 + k];
    }
}

// ---------------- reduce partials + squash -> v[b][o][k] (writes ws v or d_out)
__global__ __launch_bounds__(256) void squashv_kernel(
    const float* __restrict__ s_part, float* __restrict__ v, float scale) {
    int idx = blockIdx.x * 256 + threadIdx.x;  // b*1024 + o*16 + k
    float acc = 0.f;
    #pragma unroll
    for (int it = 0; it < 12; ++it) acc += s_part[(size_t)it * 131072 + idx];
    acc *= scale;
    float n2 = acc * acc;
    n2 += __shfl_xor(n2, 1, 64);
    n2 += __shfl_xor(n2, 2, 64);
    n2 += __shfl_xor(n2, 4, 64);
    n2 += __shfl_xor(n2, 8, 64);
    float n = sqrtf(n2);
    v[idx] = acc * n / (1.f + n2);
}

// ---------------- b-pass: blog[o][i][b] (+)= sum_k (W[i,o]@u[b,i])[k] * v[b,o,k]
template <bool ACCUM>
__global__ __launch_bounds__(256) void bpass_kernel(
    const float* __restrict__ W, const float* __restrict__ u_t,
    const float* __restrict__ v, float* __restrict__ blog) {
    int o = blockIdx.x, it = blockIdx.y;
    int b = threadIdx.x & 127;
    int ty = threadIdx.x >> 7;
    int i0 = it * 64 + ty * 32;
    float vv[16];
    const float4* vp = (const float4*)(v + ((size_t)b * 64 + o) * 16);
    #pragma unroll
    for (int q = 0; q < 4; ++q) {
        float4 t = vp[q];
        vv[q * 4 + 0] = t.x; vv[q * 4 + 1] = t.y; vv[q * 4 + 2] = t.z; vv[q * 4 + 3] = t.w;
    }
    const float* ub = u_t + (size_t)i0 * 1024 + b * 8;
    float* bl = blog + ((size_t)o * 768 + i0) * 128 + b;
    #pragma unroll 2
    for (int ii = 0; ii < 32; ++ii) {
        float4 u0 = *(const float4*)(ub + ii * 1024);
        float4 u1 = *(const float4*)(ub + ii * 1024 + 4);
        float uu[8];
        uu[0] = u0.x; uu[1] = u0.y; uu[2] = u0.z; uu[3] = u0.w;
        uu[4] = u1.x; uu[5] = u1.y; uu[6] = u1.z; uu[7] = u1.w;
        int base = __builtin_amdgcn_readfirstlane((i0 + ii) * 8192 + o * 128);
        const float* wp = W + base;
        float delta = 0.f;
        #pragma unroll
        for (int k = 0; k < 16; ++k) {
            float wd = wp[k * 8 + 0] * uu[0] + wp[k * 8 + 1] * uu[1]
                     + wp[k * 8 + 2] * uu[2] + wp[k * 8 + 3] * uu[3]
                     + wp[k * 8 + 4] * uu[4] + wp[k * 8 + 5] * uu[5]
                     + wp[k * 8 + 6] * uu[6] + wp[k * 8 + 7] * uu[7];
            delta += vv[k] * wd;
        }
        if (ACCUM) bl[ii * 128] += delta;
        else bl[ii * 128] = delta;
    }
}

// ---------------- softmax over o: c_t[o][i][b] = softmax_o(blog[o][i][b])
__global__ __launch_bounds__(128) void softmax_kernel(
    const float* __restrict__ blog, float* __restrict__ c_t) {
    int i = blockIdx.x;   // 0..767
    int b = threadIdx.x;  // 0..127
    const float* src = blog + (size_t)i * 128 + b;
    float r[64];
    float m = -1e30f;
    #pragma unroll
    for (int o = 0; o < 64; ++o) {
        r[o] = src[(size_t)o * 98304];
        m = fmaxf(m, r[o]);
    }
    float sum = 0.f;
    #pragma unroll
    for (int o = 0; o < 64; ++o) {
        r[o] = __expf(r[o] - m);
        sum += r[o];
    }
    float inv = 1.f / sum;
    float* dst = c_t + (size_t)i * 128 + b;
    #pragma unroll
    for (int o = 0; o < 64; ++o) dst[(size_t)o * 98304] = r[o] * inv;
}

extern "C" void kernel_launch(void* const* d_in, const int* in_sizes, int n_in,
                              void* d_out, int out_size, void* d_ws, size_t ws_size,
                              hipStream_t stream) {
    const float* x  = (const float*)d_in[0];
    const float* w1 = (const float*)d_in[1];
    const float* b1 = (const float*)d_in[2];
    const float* wp = (const float*)d_in[3];
    const float* bp = (const float*)d_in[4];
    const float* W  = (const float*)d_in[5];
    float* out = (float*)d_out;
    float* ws = (float*)d_ws;

    float* u_t    = ws;                  // 786432
    float* c_t    = ws + 786432;         // 6291456
    float* blog   = ws + 7077888;        // 6291456
    float* v      = ws + 13369344;       // 131072
    float* h1     = ws + 13500416;       // 479232 (region reused by s_part)
    float* s_part = ws + 13500416;       // 1572864

    conv1_kernel<<<1872, 256, 0, stream>>>(x, w1, b1, h1);
    pc_kernel<<<dim3(128, 32), 192, 0, stream>>>(h1, wp, bp, u_t);

    // iteration 0: c uniform (1/64 folded into squash scale)
    spass_kernel<true><<<dim3(64, 12), 256, 0, stream>>>(W, u_t, nullptr, s_part);
    squashv_kernel<<<512, 256, 0, stream>>>(s_part, v, 1.f / 64.f);
    bpass_kernel<false><<<dim3(64, 12), 256, 0, stream>>>(W, u_t, v, blog);

    // iteration 1
    softmax_kernel<<<768, 128, 0, stream>>>(blog, c_t);
    spass_kernel<false><<<dim3(64, 12), 256, 0, stream>>>(W, u_t, c_t, s_part);
    squashv_kernel<<<512, 256, 0, stream>>>(s_part, v, 1.f);
    bpass_kernel<true><<<dim3(64, 12), 256, 0, stream>>>(W, u_t, v, blog);

    // final
    softmax_kernel<<<768, 128, 0, stream>>>(blog, c_t);
    spass_kernel<false><<<dim3(64, 12), 256, 0, stream>>>(W, u_t, c_t, s_part);
    squashv_kernel<<<512, 256, 0, stream>>>(s_part, out, 1.f);
}

// Round 3
// 239.718 us; speedup vs baseline: 2.5265x; 2.1148x over previous
//
#include <hip/hip_runtime.h>
#include <math.h>

#define BATCH 128
#define NCI 768
#define NCO 64
#define DIN 8
#define DOUT 16

typedef __attribute__((ext_vector_type(8))) short bfrag;   // 8 bf16 = 4 VGPR
typedef __attribute__((ext_vector_type(4))) float f32x4;   // MFMA accumulator

// split 8 f32 into bf16 hi (truncation) + bf16 lo (truncation of remainder).
// x = hi + lo with |err| ~ 2^-16 |x|; 3-term MFMA (hh + hl + lh) ~ fp32 precision.
__device__ __forceinline__ void split8(const float* x, bfrag& hi, bfrag& lo) {
    #pragma unroll
    for (int j = 0; j < 8; ++j) {
        unsigned xb = __float_as_uint(x[j]);
        unsigned hb = xb & 0xffff0000u;
        float lf = x[j] - __uint_as_float(hb);
        hi[j] = (short)(xb >> 16);
        lo[j] = (short)(__float_as_uint(lf) >> 16);
    }
}

// ---------------- conv1: x(128,3,32,42) w(32,3,6,6) stride 3 -> h1(128,32,9,13), relu
__global__ __launch_bounds__(256) void conv1_kernel(
    const float* __restrict__ x, const float* __restrict__ w,
    const float* __restrict__ bias, float* __restrict__ h1) {
    __shared__ float wl[32 * 3 * 36];
    for (int i = threadIdx.x; i < 3456; i += 256) wl[i] = w[i];
    __syncthreads();
    int idx = blockIdx.x * 256 + threadIdx.x;
    const int total = BATCH * 32 * 9 * 13;
    if (idx >= total) return;
    int ow = idx % 13; int t = idx / 13;
    int oh = t % 9; t /= 9;
    int oc = t % 32; int b = t / 32;
    float acc = bias[oc];
    const float* xb = x + (size_t)b * 3 * 32 * 42;
    #pragma unroll
    for (int ic = 0; ic < 3; ++ic) {
        const float* xc = xb + ic * 32 * 42 + (oh * 3) * 42 + ow * 3;
        const float* wc = wl + (oc * 3 + ic) * 36;
        #pragma unroll
        for (int kh = 0; kh < 6; ++kh)
            #pragma unroll
            for (int kw = 0; kw < 6; ++kw)
                acc += xc[kh * 42 + kw] * wc[kh * 6 + kw];
    }
    h1[idx] = fmaxf(acc, 0.f);
}

// ---------------- primary caps conv (k=3,s=2) + squash -> u_t[i][b][d]  (768*128*8)
__global__ __launch_bounds__(192) void pc_kernel(
    const float* __restrict__ h1, const float* __restrict__ w,
    const float* __restrict__ bias, float* __restrict__ u_t) {
    __shared__ float hl[32 * 9 * 13];
    __shared__ float wl[8 * 32 * 9];
    int b = blockIdx.x, cg = blockIdx.y;
    const float* hb = h1 + (size_t)b * 3744;
    for (int i = threadIdx.x; i < 3744; i += 192) hl[i] = hb[i];
    const float* wg = w + (size_t)cg * 8 * 288;
    for (int i = threadIdx.x; i < 2304; i += 192) wl[i] = wg[i];
    __syncthreads();
    int s = threadIdx.x % 24;
    int c2l = threadIdx.x / 24;
    int h = s / 6, wc = s % 6;
    int c2 = cg * 8 + c2l;
    float acc = bias[c2];
    const float* wp0 = wl + c2l * 288;
    #pragma unroll 4
    for (int ic = 0; ic < 32; ++ic) {
        const float* hp = hl + ic * 117 + (h * 2) * 13 + wc * 2;
        const float* wp = wp0 + ic * 9;
        acc += hp[0] * wp[0] + hp[1] * wp[1] + hp[2] * wp[2]
             + hp[13] * wp[3] + hp[14] * wp[4] + hp[15] * wp[5]
             + hp[26] * wp[6] + hp[27] * wp[7] + hp[28] * wp[8];
    }
    float n2 = acc * acc;
    n2 += __shfl_xor(n2, 1, 64);
    n2 += __shfl_xor(n2, 2, 64);
    n2 += __shfl_xor(n2, 4, 64);
    float n = sqrtf(n2);
    float val = acc * n / (1.f + n2);
    int gi = cg * 192 + threadIdx.x;
    u_t[(size_t)(gi >> 3) * 1024 + b * 8 + (gi & 7)] = val;
}

// ---------------- s-pass (MFMA): per (o, it): s_part[it][b][o][k] = sum_{64 caps} c*(W@u)
// GEMM: D[b=128,k=16] += A[b,(i,d)] x B[(i,d),k], A = c*u (split bf16), B = W (split bf16).
// A-frag lane l: row b=l&15, k-elems = cap(l>>4), d=0..7 -> u[cap][b][0..7] direct.
// B-frag lane l: col k=l&15, same k-elems -> W[cap][o][k*8..+8] direct. No LDS.
template <bool UNIFORM>
__global__ __launch_bounds__(256) void spass_kernel(
    const float* __restrict__ W, const float* __restrict__ u_t,
    const float* __restrict__ c_t, float* __restrict__ s_part) {
    int o = blockIdx.x;        // 0..63
    int it = blockIdx.y;       // 0..11 (64 caps)
    int wv = threadIdx.x >> 6; // wave -> b rows [wv*32, wv*32+32)
    int l = threadIdx.x & 63;
    int q = l >> 4, r16 = l & 15;
    int i0 = it * 64;
    f32x4 acc0 = {0.f, 0.f, 0.f, 0.f};
    f32x4 acc1 = {0.f, 0.f, 0.f, 0.f};
    for (int ch = 0; ch < 8; ++ch) {          // 8 caps per chunk
        #pragma unroll
        for (int ks = 0; ks < 2; ++ks) {      // 4 caps per MFMA K-step
            int cap = i0 + ch * 8 + ks * 4 + q;
            const float* wp = W + ((size_t)cap * 64 + o) * 128 + r16 * 8;
            float wv8[8];
            *(float4*)(wv8) = *(const float4*)wp;
            *(float4*)(wv8 + 4) = *(const float4*)(wp + 4);
            bfrag bhi, blo;
            split8(wv8, bhi, blo);
            #pragma unroll
            for (int m = 0; m < 2; ++m) {
                int b = wv * 32 + m * 16 + r16;
                const float* up = u_t + ((size_t)cap * 128 + b) * 8;
                float uv[8];
                *(float4*)(uv) = *(const float4*)up;
                *(float4*)(uv + 4) = *(const float4*)(up + 4);
                if (!UNIFORM) {
                    float c = c_t[((size_t)o * 768 + cap) * 128 + b];
                    #pragma unroll
                    for (int j = 0; j < 8; ++j) uv[j] *= c;
                }
                bfrag ahi, alo;
                split8(uv, ahi, alo);
                if (m == 0) {
                    acc0 = __builtin_amdgcn_mfma_f32_16x16x32_bf16(ahi, bhi, acc0, 0, 0, 0);
                    acc0 = __builtin_amdgcn_mfma_f32_16x16x32_bf16(ahi, blo, acc0, 0, 0, 0);
                    acc0 = __builtin_amdgcn_mfma_f32_16x16x32_bf16(alo, bhi, acc0, 0, 0, 0);
                } else {
                    acc1 = __builtin_amdgcn_mfma_f32_16x16x32_bf16(ahi, bhi, acc1, 0, 0, 0);
                    acc1 = __builtin_amdgcn_mfma_f32_16x16x32_bf16(ahi, blo, acc1, 0, 0, 0);
                    acc1 = __builtin_amdgcn_mfma_f32_16x16x32_bf16(alo, bhi, acc1, 0, 0, 0);
                }
            }
        }
    }
    // C/D: col=l&15 (=k), row=(l>>4)*4+reg (b within 16-tile)  [m89-verified]
    #pragma unroll
    for (int reg = 0; reg < 4; ++reg) {
        int b0 = wv * 32 + q * 4 + reg;
        s_part[(((size_t)it * 128 + b0) * 64 + o) * 16 + r16] = acc0[reg];
        int b1 = b0 + 16;
        s_part[(((size_t)it * 128 + b1) * 64 + o) * 16 + r16] = acc1[reg];
    }
}

// ---------------- reduce partials + squash -> v[b][o][k]
__global__ __launch_bounds__(256) void squashv_kernel(
    const float* __restrict__ s_part, float* __restrict__ v, float scale) {
    int idx = blockIdx.x * 256 + threadIdx.x;  // b*1024 + o*16 + k
    float acc = 0.f;
    #pragma unroll
    for (int it = 0; it < 12; ++it) acc += s_part[(size_t)it * 131072 + idx];
    acc *= scale;
    float n2 = acc * acc;
    n2 += __shfl_xor(n2, 1, 64);
    n2 += __shfl_xor(n2, 2, 64);
    n2 += __shfl_xor(n2, 4, 64);
    n2 += __shfl_xor(n2, 8, 64);
    float n = sqrtf(n2);
    v[idx] = acc * n / (1.f + n2);
}

// ---------------- b-pass (MFMA): blog[o][i][b] (+)= sum_d u[b,i,d] * Wv[(i,d), b]
// Wv = W x v per o: M=(i,d) rows, N=b, K=16 (padded to 32; lanes q>=2 hold zero K-elems).
// A-frag lane l: row=(i_sub,d)=(l&15), k=q*8+j -> W[cap][o][k][d] (8 strided dwords, q<2).
// B-frag lane l: col=b=l&15(+n*16), k=q*8+j -> v[b][o][q*8..+8] (q<2).
// step2 fused: d-dot with u + shfl_xor(16), lanes q even write blog.
template <bool ACCUM>
__global__ __launch_bounds__(256) void bpass_kernel(
    const float* __restrict__ W, const float* __restrict__ u_t,
    const float* __restrict__ v, float* __restrict__ blog) {
    int o = blockIdx.x, it = blockIdx.y;
    int wv = threadIdx.x >> 6;
    int l = threadIdx.x & 63;
    int q = l >> 4, c16 = l & 15;
    int i0 = it * 64 + wv * 16;  // this wave's 16 caps
    // hoist v-frags (same for all Mtiles): n-th Ntile covers b = n*16 + c16
    bfrag vhi[8], vlo[8];
    #pragma unroll
    for (int n = 0; n < 8; ++n) {
        if (q < 2) {
            int b = n * 16 + c16;
            const float* vp = v + ((size_t)b * 64 + o) * 16 + q * 8;
            float vv8[8];
            *(float4*)(vv8) = *(const float4*)vp;
            *(float4*)(vv8 + 4) = *(const float4*)(vp + 4);
            split8(vv8, vhi[n], vlo[n]);
        } else {
            vhi[n] = (bfrag){0,0,0,0,0,0,0,0};
            vlo[n] = (bfrag){0,0,0,0,0,0,0,0};
        }
    }
    for (int mt = 0; mt < 8; ++mt) {   // 2 caps per Mtile
        int capA = i0 + mt * 2 + (c16 >> 3);
        int d = c16 & 7;
        bfrag whiF = {0,0,0,0,0,0,0,0}, wloF = {0,0,0,0,0,0,0,0};
        if (q < 2) {
            const float* wp = W + ((size_t)capA * 64 + o) * 128 + (q * 8) * 8 + d;
            float wv8[8];
            #pragma unroll
            for (int j = 0; j < 8; ++j) wv8[j] = wp[j * 8];
            split8(wv8, whiF, wloF);
        }
        f32x4 acc[8];
        #pragma unroll
        for (int n = 0; n < 8; ++n) acc[n] = (f32x4){0.f, 0.f, 0.f, 0.f};
        #pragma unroll
        for (int n = 0; n < 8; ++n) {
            acc[n] = __builtin_amdgcn_mfma_f32_16x16x32_bf16(whiF, vhi[n], acc[n], 0, 0, 0);
            acc[n] = __builtin_amdgcn_mfma_f32_16x16x32_bf16(whiF, vlo[n], acc[n], 0, 0, 0);
            acc[n] = __builtin_amdgcn_mfma_f32_16x16x32_bf16(wloF, vhi[n], acc[n], 0, 0, 0);
        }
        // step2: lane holds Wv rows 4q..4q+3 (cap = mt*2+(q>>1), d = (q&1)*4 + r), col b=n*16+c16
        int cap2 = i0 + mt * 2 + (q >> 1);
        #pragma unroll
        for (int n = 0; n < 8; ++n) {
            int b = n * 16 + c16;
            const float* up = u_t + ((size_t)cap2 * 128 + b) * 8 + (q & 1) * 4;
            float4 u4 = *(const float4*)up;
            float part = u4.x * acc[n][0] + u4.y * acc[n][1]
                       + u4.z * acc[n][2] + u4.w * acc[n][3];
            float full = part + __shfl_xor(part, 16, 64);
            if (!(q & 1)) {
                size_t bi = ((size_t)o * 768 + cap2) * 128 + b;
                float prev = ACCUM ? blog[bi] : 0.f;
                blog[bi] = prev + full;
            }
        }
    }
}

// ---------------- softmax over o: c_t[o][i][b] = softmax_o(blog[o][i][b])
__global__ __launch_bounds__(128) void softmax_kernel(
    const float* __restrict__ blog, float* __restrict__ c_t) {
    int i = blockIdx.x;
    int b = threadIdx.x;
    const float* src = blog + (size_t)i * 128 + b;
    float r[64];
    float m = -1e30f;
    #pragma unroll
    for (int o = 0; o < 64; ++o) {
        r[o] = src[(size_t)o * 98304];
        m = fmaxf(m, r[o]);
    }
    float sum = 0.f;
    #pragma unroll
    for (int o = 0; o < 64; ++o) {
        r[o] = __expf(r[o] - m);
        sum += r[o];
    }
    float inv = 1.f / sum;
    float* dst = c_t + (size_t)i * 128 + b;
    #pragma unroll
    for (int o = 0; o < 64; ++o) dst[(size_t)o * 98304] = r[o] * inv;
}

extern "C" void kernel_launch(void* const* d_in, const int* in_sizes, int n_in,
                              void* d_out, int out_size, void* d_ws, size_t ws_size,
                              hipStream_t stream) {
    const float* x  = (const float*)d_in[0];
    const float* w1 = (const float*)d_in[1];
    const float* b1 = (const float*)d_in[2];
    const float* wp = (const float*)d_in[3];
    const float* bp = (const float*)d_in[4];
    const float* W  = (const float*)d_in[5];
    float* out = (float*)d_out;
    float* ws = (float*)d_ws;

    float* u_t    = ws;                  // 786432
    float* c_t    = ws + 786432;         // 6291456
    float* blog   = ws + 7077888;        // 6291456
    float* v      = ws + 13369344;       // 131072
    float* h1     = ws + 13500416;       // 479232 (region reused by s_part)
    float* s_part = ws + 13500416;       // 1572864

    conv1_kernel<<<1872, 256, 0, stream>>>(x, w1, b1, h1);
    pc_kernel<<<dim3(128, 32), 192, 0, stream>>>(h1, wp, bp, u_t);

    // iteration 0: c uniform (1/64 folded into squash scale)
    spass_kernel<true><<<dim3(64, 12), 256, 0, stream>>>(W, u_t, nullptr, s_part);
    squashv_kernel<<<512, 256, 0, stream>>>(s_part, v, 1.f / 64.f);
    bpass_kernel<false><<<dim3(64, 12), 256, 0, stream>>>(W, u_t, v, blog);

    // iteration 1
    softmax_kernel<<<768, 128, 0, stream>>>(blog, c_t);
    spass_kernel<false><<<dim3(64, 12), 256, 0, stream>>>(W, u_t, c_t, s_part);
    squashv_kernel<<<512, 256, 0, stream>>>(s_part, v, 1.f);
    bpass_kernel<true><<<dim3(64, 12), 256, 0, stream>>>(W, u_t, v, blog);

    // final
    softmax_kernel<<<768, 128, 0, stream>>>(blog, c_t);
    spass_kernel<false><<<dim3(64, 12), 256, 0, stream>>>(W, u_t, c_t, s_part);
    squashv_kernel<<<512, 256, 0, stream>>>(s_part, out, 1.f);
}

// Round 4
// 204.924 us; speedup vs baseline: 2.9555x; 1.1698x over previous
//
#include <hip/hip_runtime.h>
#include <math.h>

#define BATCH 128
#define NCI 768
#define NCO 64
#define DIN 8
#define DOUT 16

typedef __attribute__((ext_vector_type(8))) short bfrag;   // 8 bf16 = 4 VGPR
typedef __attribute__((ext_vector_type(4))) float f32x4;   // MFMA accumulator

// split 8 f32 into bf16 hi (truncation) + bf16 lo (truncation of remainder).
// x = hi + lo with |err| ~ 2^-16 |x|; 3-term MFMA (hh + hl + lh) ~ fp32 precision.
__device__ __forceinline__ void split8(const float* x, bfrag& hi, bfrag& lo) {
    #pragma unroll
    for (int j = 0; j < 8; ++j) {
        unsigned xb = __float_as_uint(x[j]);
        unsigned hb = xb & 0xffff0000u;
        float lf = x[j] - __uint_as_float(hb);
        hi[j] = (short)(xb >> 16);
        lo[j] = (short)(__float_as_uint(lf) >> 16);
    }
}

// ---------------- conv1: x(128,3,32,42) w(32,3,6,6) stride 3 -> h1(128,32,9,13), relu
__global__ __launch_bounds__(256) void conv1_kernel(
    const float* __restrict__ x, const float* __restrict__ w,
    const float* __restrict__ bias, float* __restrict__ h1) {
    __shared__ float wl[32 * 3 * 36];
    for (int i = threadIdx.x; i < 3456; i += 256) wl[i] = w[i];
    __syncthreads();
    int idx = blockIdx.x * 256 + threadIdx.x;
    const int total = BATCH * 32 * 9 * 13;
    if (idx >= total) return;
    int ow = idx % 13; int t = idx / 13;
    int oh = t % 9; t /= 9;
    int oc = t % 32; int b = t / 32;
    float acc = bias[oc];
    const float* xb = x + (size_t)b * 3 * 32 * 42;
    #pragma unroll
    for (int ic = 0; ic < 3; ++ic) {
        const float* xc = xb + ic * 32 * 42 + (oh * 3) * 42 + ow * 3;
        const float* wc = wl + (oc * 3 + ic) * 36;
        #pragma unroll
        for (int kh = 0; kh < 6; ++kh)
            #pragma unroll
            for (int kw = 0; kw < 6; ++kw)
                acc += xc[kh * 42 + kw] * wc[kh * 6 + kw];
    }
    h1[idx] = fmaxf(acc, 0.f);
}

// ---------------- im2col for primary-caps conv: B2[ko][n][j], ko=K-octet (36), n=(b,s) (3072)
// k = ko*8+j = ic*9 + kh*3 + kw ; n = b*24 + s, s = h*6+w ; src = h1[b, ic, 2h+kh, 2w+kw]
__global__ __launch_bounds__(256) void im2col_kernel(
    const float* __restrict__ h1, float* __restrict__ B2) {
    int idx = blockIdx.x * 256 + threadIdx.x;
    if (idx >= 36 * 3072) return;
    int n = idx % 3072, ko = idx / 3072;
    int b = n / 24, s = n % 24, h = s / 6, w = s % 6;
    const float* hb = h1 + (size_t)b * 3744 + (2 * h) * 13 + 2 * w;
    float out[8];
    #pragma unroll
    for (int j = 0; j < 8; ++j) {
        int k = ko * 8 + j;
        int ic = k / 9, r = k % 9;
        int kh = r / 3, kw = r % 3;
        out[j] = hb[ic * 117 + kh * 13 + kw];
    }
    *(float4*)(B2 + (size_t)idx * 8) = *(const float4*)out;
    *(float4*)(B2 + (size_t)idx * 8 + 4) = *(const float4*)(out + 4);
}

// ---------------- pc GEMM (MFMA) + bias + squash -> u_t[i][b][d]
// D[c2=256, n=(b,s)=3072] = Wpc[c2, K=288] x B2 ; squash over s-octets (= capsule dim d)
__global__ __launch_bounds__(256) void pc_gemm_kernel(
    const float* __restrict__ wpc, const float* __restrict__ bias,
    const float* __restrict__ B2, float* __restrict__ u_t) {
    int wv = threadIdx.x >> 6;
    int l = threadIdx.x & 63;
    int q = l >> 4, r16 = l & 15;
    int c2t = blockIdx.y * 4 + wv;     // 0..15
    int n0 = blockIdx.x * 16;          // 0..3056
    f32x4 acc = {0.f, 0.f, 0.f, 0.f};
    int c2a = c2t * 16 + r16;          // A-fragment row
    const float* ap0 = wpc + (size_t)c2a * 288 + q * 8;
    const float* bp0 = B2 + ((size_t)q * 3072 + n0 + r16) * 8;
    #pragma unroll
    for (int ks = 0; ks < 9; ++ks) {
        float av[8], bv[8];
        *(float4*)av = *(const float4*)(ap0 + ks * 32);
        *(float4*)(av + 4) = *(const float4*)(ap0 + ks * 32 + 4);
        *(float4*)bv = *(const float4*)(bp0 + (size_t)ks * 4 * 3072 * 8);
        *(float4*)(bv + 4) = *(const float4*)(bp0 + (size_t)ks * 4 * 3072 * 8 + 4);
        bfrag ahi, alo, bhi, blo;
        split8(av, ahi, alo);
        split8(bv, bhi, blo);
        acc = __builtin_amdgcn_mfma_f32_16x16x32_bf16(ahi, bhi, acc, 0, 0, 0);
        acc = __builtin_amdgcn_mfma_f32_16x16x32_bf16(ahi, blo, acc, 0, 0, 0);
        acc = __builtin_amdgcn_mfma_f32_16x16x32_bf16(alo, bhi, acc, 0, 0, 0);
    }
    // D: col n = n0 + r16, row c2 = c2t*16 + q*4 + reg  [m89]
    int n = n0 + r16;
    int b = n / 24, s = n % 24;
    float vals[4], n2[4];
    #pragma unroll
    for (int r = 0; r < 4; ++r) {
        float xv = acc[r] + bias[c2t * 16 + q * 4 + r];
        vals[r] = xv;
        n2[r] = xv * xv;
    }
    #pragma unroll
    for (int r = 0; r < 4; ++r) {
        n2[r] += __shfl_xor(n2[r], 1, 64);
        n2[r] += __shfl_xor(n2[r], 2, 64);
        n2[r] += __shfl_xor(n2[r], 4, 64);
    }
    #pragma unroll
    for (int r = 0; r < 4; ++r) {
        int c2 = c2t * 16 + q * 4 + r;
        int cap = c2 * 3 + (s >> 3);
        int d = s & 7;
        float nr = sqrtf(n2[r]);
        u_t[((size_t)cap * 128 + b) * 8 + d] = vals[r] * nr / (1.f + n2[r]);
    }
}

// ---------------- s-pass (MFMA): per (o, it): s_part[it][b][o][k] = sum_{64 caps} c*(W@u)
template <bool UNIFORM>
__global__ __launch_bounds__(256) void spass_kernel(
    const float* __restrict__ W, const float* __restrict__ u_t,
    const float* __restrict__ c_t, float* __restrict__ s_part) {
    int o = blockIdx.x;
    int it = blockIdx.y;
    int wv = threadIdx.x >> 6;
    int l = threadIdx.x & 63;
    int q = l >> 4, r16 = l & 15;
    int i0 = it * 64;
    f32x4 acc0 = {0.f, 0.f, 0.f, 0.f};
    f32x4 acc1 = {0.f, 0.f, 0.f, 0.f};
    for (int ch = 0; ch < 8; ++ch) {
        #pragma unroll
        for (int ks = 0; ks < 2; ++ks) {
            int cap = i0 + ch * 8 + ks * 4 + q;
            const float* wp = W + ((size_t)cap * 64 + o) * 128 + r16 * 8;
            float wv8[8];
            *(float4*)(wv8) = *(const float4*)wp;
            *(float4*)(wv8 + 4) = *(const float4*)(wp + 4);
            bfrag bhi, blo;
            split8(wv8, bhi, blo);
            #pragma unroll
            for (int m = 0; m < 2; ++m) {
                int b = wv * 32 + m * 16 + r16;
                const float* up = u_t + ((size_t)cap * 128 + b) * 8;
                float uv[8];
                *(float4*)(uv) = *(const float4*)up;
                *(float4*)(uv + 4) = *(const float4*)(up + 4);
                if (!UNIFORM) {
                    float c = c_t[((size_t)o * 768 + cap) * 128 + b];
                    #pragma unroll
                    for (int j = 0; j < 8; ++j) uv[j] *= c;
                }
                bfrag ahi, alo;
                split8(uv, ahi, alo);
                if (m == 0) {
                    acc0 = __builtin_amdgcn_mfma_f32_16x16x32_bf16(ahi, bhi, acc0, 0, 0, 0);
                    acc0 = __builtin_amdgcn_mfma_f32_16x16x32_bf16(ahi, blo, acc0, 0, 0, 0);
                    acc0 = __builtin_amdgcn_mfma_f32_16x16x32_bf16(alo, bhi, acc0, 0, 0, 0);
                } else {
                    acc1 = __builtin_amdgcn_mfma_f32_16x16x32_bf16(ahi, bhi, acc1, 0, 0, 0);
                    acc1 = __builtin_amdgcn_mfma_f32_16x16x32_bf16(ahi, blo, acc1, 0, 0, 0);
                    acc1 = __builtin_amdgcn_mfma_f32_16x16x32_bf16(alo, bhi, acc1, 0, 0, 0);
                }
            }
        }
    }
    #pragma unroll
    for (int reg = 0; reg < 4; ++reg) {
        int b0 = wv * 32 + q * 4 + reg;
        s_part[(((size_t)it * 128 + b0) * 64 + o) * 16 + r16] = acc0[reg];
        int b1 = b0 + 16;
        s_part[(((size_t)it * 128 + b1) * 64 + o) * 16 + r16] = acc1[reg];
    }
}

// ---------------- reduce partials + squash -> v[b][o][k]
__global__ __launch_bounds__(256) void squashv_kernel(
    const float* __restrict__ s_part, float* __restrict__ v, float scale) {
    int idx = blockIdx.x * 256 + threadIdx.x;
    float acc = 0.f;
    #pragma unroll
    for (int it = 0; it < 12; ++it) acc += s_part[(size_t)it * 131072 + idx];
    acc *= scale;
    float n2 = acc * acc;
    n2 += __shfl_xor(n2, 1, 64);
    n2 += __shfl_xor(n2, 2, 64);
    n2 += __shfl_xor(n2, 4, 64);
    n2 += __shfl_xor(n2, 8, 64);
    float n = sqrtf(n2);
    v[idx] = acc * n / (1.f + n2);
}

// ---------------- b-pass (MFMA): blog[o][i][b] (+)= sum_d u[b,i,d] * (W x v)[(i,d), b]
template <bool ACCUM>
__global__ __launch_bounds__(256) void bpass_kernel(
    const float* __restrict__ W, const float* __restrict__ u_t,
    const float* __restrict__ v, float* __restrict__ blog) {
    int o = blockIdx.x, it = blockIdx.y;
    int wv = threadIdx.x >> 6;
    int l = threadIdx.x & 63;
    int q = l >> 4, c16 = l & 15;
    int i0 = it * 64 + wv * 16;
    bfrag vhi[8], vlo[8];
    #pragma unroll
    for (int n = 0; n < 8; ++n) {
        if (q < 2) {
            int b = n * 16 + c16;
            const float* vp = v + ((size_t)b * 64 + o) * 16 + q * 8;
            float vv8[8];
            *(float4*)(vv8) = *(const float4*)vp;
            *(float4*)(vv8 + 4) = *(const float4*)(vp + 4);
            split8(vv8, vhi[n], vlo[n]);
        } else {
            vhi[n] = (bfrag){0,0,0,0,0,0,0,0};
            vlo[n] = (bfrag){0,0,0,0,0,0,0,0};
        }
    }
    for (int mt = 0; mt < 8; ++mt) {
        int capA = i0 + mt * 2 + (c16 >> 3);
        int d = c16 & 7;
        bfrag whiF = {0,0,0,0,0,0,0,0}, wloF = {0,0,0,0,0,0,0,0};
        if (q < 2) {
            const float* wp = W + ((size_t)capA * 64 + o) * 128 + (q * 8) * 8 + d;
            float wv8[8];
            #pragma unroll
            for (int j = 0; j < 8; ++j) wv8[j] = wp[j * 8];
            split8(wv8, whiF, wloF);
        }
        f32x4 acc[8];
        #pragma unroll
        for (int n = 0; n < 8; ++n) acc[n] = (f32x4){0.f, 0.f, 0.f, 0.f};
        #pragma unroll
        for (int n = 0; n < 8; ++n) {
            acc[n] = __builtin_amdgcn_mfma_f32_16x16x32_bf16(whiF, vhi[n], acc[n], 0, 0, 0);
            acc[n] = __builtin_amdgcn_mfma_f32_16x16x32_bf16(whiF, vlo[n], acc[n], 0, 0, 0);
            acc[n] = __builtin_amdgcn_mfma_f32_16x16x32_bf16(wloF, vhi[n], acc[n], 0, 0, 0);
        }
        int cap2 = i0 + mt * 2 + (q >> 1);
        #pragma unroll
        for (int n = 0; n < 8; ++n) {
            int b = n * 16 + c16;
            const float* up = u_t + ((size_t)cap2 * 128 + b) * 8 + (q & 1) * 4;
            float4 u4 = *(const float4*)up;
            float part = u4.x * acc[n][0] + u4.y * acc[n][1]
                       + u4.z * acc[n][2] + u4.w * acc[n][3];
            float full = part + __shfl_xor(part, 16, 64);
            if (!(q & 1)) {
                size_t bi = ((size_t)o * 768 + cap2) * 128 + b;
                float prev = ACCUM ? blog[bi] : 0.f;
                blog[bi] = prev + full;
            }
        }
    }
}

// ---------------- softmax over o: c_t[o][i][b] = softmax_o(blog[o][i][b])
__global__ __launch_bounds__(128) void softmax_kernel(
    const float* __restrict__ blog, float* __restrict__ c_t) {
    int i = blockIdx.x;
    int b = threadIdx.x;
    const float* src = blog + (size_t)i * 128 + b;
    float r[64];
    float m = -1e30f;
    #pragma unroll
    for (int o = 0; o < 64; ++o) {
        r[o] = src[(size_t)o * 98304];
        m = fmaxf(m, r[o]);
    }
    float sum = 0.f;
    #pragma unroll
    for (int o = 0; o < 64; ++o) {
        r[o] = __expf(r[o] - m);
        sum += r[o];
    }
    float inv = 1.f / sum;
    float* dst = c_t + (size_t)i * 128 + b;
    #pragma unroll
    for (int o = 0; o < 64; ++o) dst[(size_t)o * 98304] = r[o] * inv;
}

extern "C" void kernel_launch(void* const* d_in, const int* in_sizes, int n_in,
                              void* d_out, int out_size, void* d_ws, size_t ws_size,
                              hipStream_t stream) {
    const float* x  = (const float*)d_in[0];
    const float* w1 = (const float*)d_in[1];
    const float* b1 = (const float*)d_in[2];
    const float* wp = (const float*)d_in[3];
    const float* bp = (const float*)d_in[4];
    const float* W  = (const float*)d_in[5];
    float* out = (float*)d_out;
    float* ws = (float*)d_ws;

    float* u_t    = ws;                  // 786432
    float* c_t    = ws + 786432;         // 6291456 (B2 im2col reuses this region pre-routing)
    float* blog   = ws + 7077888;        // 6291456
    float* v      = ws + 13369344;       // 131072
    float* h1     = ws + 13500416;       // 479232 (region reused by s_part)
    float* s_part = ws + 13500416;       // 1572864
    float* B2     = c_t;                 // 884736 floats, dead before softmax writes c_t

    conv1_kernel<<<1872, 256, 0, stream>>>(x, w1, b1, h1);
    im2col_kernel<<<432, 256, 0, stream>>>(h1, B2);
    pc_gemm_kernel<<<dim3(192, 4), 256, 0, stream>>>(wp, bp, B2, u_t);

    // iteration 0: c uniform (1/64 folded into squash scale)
    spass_kernel<true><<<dim3(64, 12), 256, 0, stream>>>(W, u_t, nullptr, s_part);
    squashv_kernel<<<512, 256, 0, stream>>>(s_part, v, 1.f / 64.f);
    bpass_kernel<false><<<dim3(64, 12), 256, 0, stream>>>(W, u_t, v, blog);

    // iteration 1
    softmax_kernel<<<768, 128, 0, stream>>>(blog, c_t);
    spass_kernel<false><<<dim3(64, 12), 256, 0, stream>>>(W, u_t, c_t, s_part);
    squashv_kernel<<<512, 256, 0, stream>>>(s_part, v, 1.f);
    bpass_kernel<true><<<dim3(64, 12), 256, 0, stream>>>(W, u_t, v, blog);

    // final
    softmax_kernel<<<768, 128, 0, stream>>>(blog, c_t);
    spass_kernel<false><<<dim3(64, 12), 256, 0, stream>>>(W, u_t, c_t, s_part);
    squashv_kernel<<<512, 256, 0, stream>>>(s_part, out, 1.f);
}

// Round 5
// 203.602 us; speedup vs baseline: 2.9747x; 1.0065x over previous
//
#include <hip/hip_runtime.h>
#include <math.h>

#define BATCH 128
#define NCI 768
#define NCO 64
#define DIN 8
#define DOUT 16

typedef __attribute__((ext_vector_type(8))) short bfrag;    // 8 bf16 = 4 VGPR
typedef __attribute__((ext_vector_type(4))) float f32x4;    // 16x16 accumulator
typedef __attribute__((ext_vector_type(16))) float f32x16;  // 32x32 accumulator

// split 8 f32 into bf16 hi (truncation) + bf16 lo (truncation of remainder).
// x = hi + lo with |err| ~ 2^-16 |x|; 3-term MFMA (hh + hl + lh) ~ fp32 precision.
__device__ __forceinline__ void split8(const float* x, bfrag& hi, bfrag& lo) {
    #pragma unroll
    for (int j = 0; j < 8; ++j) {
        unsigned xb = __float_as_uint(x[j]);
        unsigned hb = xb & 0xffff0000u;
        float lf = x[j] - __uint_as_float(hb);
        hi[j] = (short)(xb >> 16);
        lo[j] = (short)(__float_as_uint(lf) >> 16);
    }
}

// ---------------- conv1: x(128,3,32,42) w(32,3,6,6) stride 3 -> h1(128,32,9,13), relu
__global__ __launch_bounds__(256) void conv1_kernel(
    const float* __restrict__ x, const float* __restrict__ w,
    const float* __restrict__ bias, float* __restrict__ h1) {
    __shared__ float wl[32 * 3 * 36];
    for (int i = threadIdx.x; i < 3456; i += 256) wl[i] = w[i];
    __syncthreads();
    int idx = blockIdx.x * 256 + threadIdx.x;
    const int total = BATCH * 32 * 9 * 13;
    if (idx >= total) return;
    int ow = idx % 13; int t = idx / 13;
    int oh = t % 9; t /= 9;
    int oc = t % 32; int b = t / 32;
    float acc = bias[oc];
    const float* xb = x + (size_t)b * 3 * 32 * 42;
    #pragma unroll
    for (int ic = 0; ic < 3; ++ic) {
        const float* xc = xb + ic * 32 * 42 + (oh * 3) * 42 + ow * 3;
        const float* wc = wl + (oc * 3 + ic) * 36;
        #pragma unroll
        for (int kh = 0; kh < 6; ++kh)
            #pragma unroll
            for (int kw = 0; kw < 6; ++kw)
                acc += xc[kh * 42 + kw] * wc[kh * 6 + kw];
    }
    h1[idx] = fmaxf(acc, 0.f);
}

// ---------------- im2col for primary-caps conv: B2[ko][n][j], ko=K-octet (36), n=(b,s) (3072)
__global__ __launch_bounds__(256) void im2col_kernel(
    const float* __restrict__ h1, float* __restrict__ B2) {
    int idx = blockIdx.x * 256 + threadIdx.x;
    if (idx >= 36 * 3072) return;
    int n = idx % 3072, ko = idx / 3072;
    int b = n / 24, s = n % 24, h = s / 6, w = s % 6;
    const float* hb = h1 + (size_t)b * 3744 + (2 * h) * 13 + 2 * w;
    float out[8];
    #pragma unroll
    for (int j = 0; j < 8; ++j) {
        int k = ko * 8 + j;
        int ic = k / 9, r = k % 9;
        int kh = r / 3, kw = r % 3;
        out[j] = hb[ic * 117 + kh * 13 + kw];
    }
    *(float4*)(B2 + (size_t)idx * 8) = *(const float4*)out;
    *(float4*)(B2 + (size_t)idx * 8 + 4) = *(const float4*)(out + 4);
}

// ---------------- pc GEMM (MFMA) + bias + squash -> u_t[i][b][d]
__global__ __launch_bounds__(256) void pc_gemm_kernel(
    const float* __restrict__ wpc, const float* __restrict__ bias,
    const float* __restrict__ B2, float* __restrict__ u_t) {
    int wv = threadIdx.x >> 6;
    int l = threadIdx.x & 63;
    int q = l >> 4, r16 = l & 15;
    int c2t = blockIdx.y * 4 + wv;
    int n0 = blockIdx.x * 16;
    f32x4 acc = {0.f, 0.f, 0.f, 0.f};
    int c2a = c2t * 16 + r16;
    const float* ap0 = wpc + (size_t)c2a * 288 + q * 8;
    const float* bp0 = B2 + ((size_t)q * 3072 + n0 + r16) * 8;
    #pragma unroll
    for (int ks = 0; ks < 9; ++ks) {
        float av[8], bv[8];
        *(float4*)av = *(const float4*)(ap0 + ks * 32);
        *(float4*)(av + 4) = *(const float4*)(ap0 + ks * 32 + 4);
        *(float4*)bv = *(const float4*)(bp0 + (size_t)ks * 4 * 3072 * 8);
        *(float4*)(bv + 4) = *(const float4*)(bp0 + (size_t)ks * 4 * 3072 * 8 + 4);
        bfrag ahi, alo, bhi, blo;
        split8(av, ahi, alo);
        split8(bv, bhi, blo);
        acc = __builtin_amdgcn_mfma_f32_16x16x32_bf16(ahi, bhi, acc, 0, 0, 0);
        acc = __builtin_amdgcn_mfma_f32_16x16x32_bf16(ahi, blo, acc, 0, 0, 0);
        acc = __builtin_amdgcn_mfma_f32_16x16x32_bf16(alo, bhi, acc, 0, 0, 0);
    }
    int n = n0 + r16;
    int b = n / 24, s = n % 24;
    float vals[4], n2[4];
    #pragma unroll
    for (int r = 0; r < 4; ++r) {
        float xv = acc[r] + bias[c2t * 16 + q * 4 + r];
        vals[r] = xv;
        n2[r] = xv * xv;
    }
    #pragma unroll
    for (int r = 0; r < 4; ++r) {
        n2[r] += __shfl_xor(n2[r], 1, 64);
        n2[r] += __shfl_xor(n2[r], 2, 64);
        n2[r] += __shfl_xor(n2[r], 4, 64);
    }
    #pragma unroll
    for (int r = 0; r < 4; ++r) {
        int c2 = c2t * 16 + q * 4 + r;
        int cap = c2 * 3 + (s >> 3);
        int d = s & 7;
        float nr = sqrtf(n2[r]);
        u_t[((size_t)cap * 128 + b) * 8 + d] = vals[r] * nr / (1.f + n2[r]);
    }
}

// ---------------- s-pass (MFMA): per (o, it): s_part[it][b][o][k] = sum_{64 caps} c*(W@u)
template <bool UNIFORM>
__global__ __launch_bounds__(256) void spass_kernel(
    const float* __restrict__ W, const float* __restrict__ u_t,
    const float* __restrict__ c_t, float* __restrict__ s_part) {
    int o = blockIdx.x;
    int it = blockIdx.y;
    int wv = threadIdx.x >> 6;
    int l = threadIdx.x & 63;
    int q = l >> 4, r16 = l & 15;
    int i0 = it * 64;
    f32x4 acc0 = {0.f, 0.f, 0.f, 0.f};
    f32x4 acc1 = {0.f, 0.f, 0.f, 0.f};
    for (int ch = 0; ch < 8; ++ch) {
        #pragma unroll
        for (int ks = 0; ks < 2; ++ks) {
            int cap = i0 + ch * 8 + ks * 4 + q;
            const float* wp = W + ((size_t)cap * 64 + o) * 128 + r16 * 8;
            float wv8[8];
            *(float4*)(wv8) = *(const float4*)wp;
            *(float4*)(wv8 + 4) = *(const float4*)(wp + 4);
            bfrag bhi, blo;
            split8(wv8, bhi, blo);
            #pragma unroll
            for (int m = 0; m < 2; ++m) {
                int b = wv * 32 + m * 16 + r16;
                const float* up = u_t + ((size_t)cap * 128 + b) * 8;
                float uv[8];
                *(float4*)(uv) = *(const float4*)up;
                *(float4*)(uv + 4) = *(const float4*)(up + 4);
                if (!UNIFORM) {
                    float c = c_t[((size_t)o * 768 + cap) * 128 + b];
                    #pragma unroll
                    for (int j = 0; j < 8; ++j) uv[j] *= c;
                }
                bfrag ahi, alo;
                split8(uv, ahi, alo);
                if (m == 0) {
                    acc0 = __builtin_amdgcn_mfma_f32_16x16x32_bf16(ahi, bhi, acc0, 0, 0, 0);
                    acc0 = __builtin_amdgcn_mfma_f32_16x16x32_bf16(ahi, blo, acc0, 0, 0, 0);
                    acc0 = __builtin_amdgcn_mfma_f32_16x16x32_bf16(alo, bhi, acc0, 0, 0, 0);
                } else {
                    acc1 = __builtin_amdgcn_mfma_f32_16x16x32_bf16(ahi, bhi, acc1, 0, 0, 0);
                    acc1 = __builtin_amdgcn_mfma_f32_16x16x32_bf16(ahi, blo, acc1, 0, 0, 0);
                    acc1 = __builtin_amdgcn_mfma_f32_16x16x32_bf16(alo, bhi, acc1, 0, 0, 0);
                }
            }
        }
    }
    #pragma unroll
    for (int reg = 0; reg < 4; ++reg) {
        int b0 = wv * 32 + q * 4 + reg;
        s_part[(((size_t)it * 128 + b0) * 64 + o) * 16 + r16] = acc0[reg];
        int b1 = b0 + 16;
        s_part[(((size_t)it * 128 + b1) * 64 + o) * 16 + r16] = acc1[reg];
    }
}

// ---------------- reduce partials + squash -> v[b][o][k]
__global__ __launch_bounds__(256) void squashv_kernel(
    const float* __restrict__ s_part, float* __restrict__ v, float scale) {
    int idx = blockIdx.x * 256 + threadIdx.x;
    float acc = 0.f;
    #pragma unroll
    for (int it = 0; it < 12; ++it) acc += s_part[(size_t)it * 131072 + idx];
    acc *= scale;
    float n2 = acc * acc;
    n2 += __shfl_xor(n2, 1, 64);
    n2 += __shfl_xor(n2, 2, 64);
    n2 += __shfl_xor(n2, 4, 64);
    n2 += __shfl_xor(n2, 8, 64);
    float n = sqrtf(n2);
    v[idx] = acc * n / (1.f + n2);
}

// ---------------- b-pass (32x32x16 MFMA, K=16 exact): per (o, it of 32 caps):
// Wv[(i,d), b] = sum_k W[i,o,k,d] v[b,o,k]; blog[o,i,b] (+)= sum_d u[b,i,d] Wv[(i,d),b]
// A-frag lane l: row r=l&31 -> cap=base+(r>>3), d=r&7; k=kh*8+j (kh=l>>5) -> 8 strided dwords.
// B-frag lane l: col b=nt*32+r; k=kh*8+j -> v[b][o][kh*8..+8] contiguous.
// C/D [m74/m101]: col=l&31, row=(reg&3)+8*(reg>>2)+4*kh -> cap-group g=reg>>2, d=(reg&3)+4*kh.
template <bool ACCUM>
__global__ __launch_bounds__(256, 4) void bpass_kernel(
    const float* __restrict__ W, const float* __restrict__ u_t,
    const float* __restrict__ v, float* __restrict__ blog) {
    int o = blockIdx.x, it = blockIdx.y;   // it: 0..23 (32 caps)
    int wv = threadIdx.x >> 6;
    int l = threadIdx.x & 63;
    int r = l & 31;
    int kh = l >> 5;
    int cap0 = it * 32 + wv * 8;           // wave's 8 caps
    // hoist B-frags (v)
    bfrag vhi[4], vlo[4];
    #pragma unroll
    for (int nt = 0; nt < 4; ++nt) {
        const float* vp = v + ((size_t)(nt * 32 + r) * 64 + o) * 16 + kh * 8;
        float vv8[8];
        *(float4*)(vv8) = *(const float4*)vp;
        *(float4*)(vv8 + 4) = *(const float4*)(vp + 4);
        split8(vv8, vhi[nt], vlo[nt]);
    }
    // prefetch both A-frag gathers
    float w8[2][8];
    #pragma unroll
    for (int mt = 0; mt < 2; ++mt) {
        const float* wp = W + ((size_t)(cap0 + mt * 4 + (r >> 3)) * 64 + o) * 128
                        + kh * 64 + (r & 7);
        #pragma unroll
        for (int j = 0; j < 8; ++j) w8[mt][j] = wp[j * 8];
    }
    #pragma unroll
    for (int mt = 0; mt < 2; ++mt) {
        bfrag ahi, alo;
        split8(w8[mt], ahi, alo);
        int capg = cap0 + mt * 4;
        #pragma unroll
        for (int nt = 0; nt < 4; ++nt) {
            f32x16 acc;
            #pragma unroll
            for (int z = 0; z < 16; ++z) acc[z] = 0.f;
            acc = __builtin_amdgcn_mfma_f32_32x32x16_bf16(ahi, vhi[nt], acc, 0, 0, 0);
            acc = __builtin_amdgcn_mfma_f32_32x32x16_bf16(ahi, vlo[nt], acc, 0, 0, 0);
            acc = __builtin_amdgcn_mfma_f32_32x32x16_bf16(alo, vhi[nt], acc, 0, 0, 0);
            int b = nt * 32 + r;
            #pragma unroll
            for (int g = 0; g < 4; ++g) {
                int cap = capg + g;
                const float* up = u_t + ((size_t)cap * 128 + b) * 8 + kh * 4;
                float4 u4 = *(const float4*)up;
                float part = u4.x * acc[g * 4 + 0] + u4.y * acc[g * 4 + 1]
                           + u4.z * acc[g * 4 + 2] + u4.w * acc[g * 4 + 3];
                float full = part + __shfl_xor(part, 32, 64);
                if (!kh) {
                    size_t bi = ((size_t)o * 768 + cap) * 128 + b;
                    blog[bi] = (ACCUM ? blog[bi] : 0.f) + full;
                }
            }
        }
    }
}

// ---------------- softmax over o: c_t[o][i][b] = softmax_o(blog[o][i][b])
__global__ __launch_bounds__(128) void softmax_kernel(
    const float* __restrict__ blog, float* __restrict__ c_t) {
    int i = blockIdx.x;
    int b = threadIdx.x;
    const float* src = blog + (size_t)i * 128 + b;
    float r[64];
    float m = -1e30f;
    #pragma unroll
    for (int o = 0; o < 64; ++o) {
        r[o] = src[(size_t)o * 98304];
        m = fmaxf(m, r[o]);
    }
    float sum = 0.f;
    #pragma unroll
    for (int o = 0; o < 64; ++o) {
        r[o] = __expf(r[o] - m);
        sum += r[o];
    }
    float inv = 1.f / sum;
    float* dst = c_t + (size_t)i * 128 + b;
    #pragma unroll
    for (int o = 0; o < 64; ++o) dst[(size_t)o * 98304] = r[o] * inv;
}

extern "C" void kernel_launch(void* const* d_in, const int* in_sizes, int n_in,
                              void* d_out, int out_size, void* d_ws, size_t ws_size,
                              hipStream_t stream) {
    const float* x  = (const float*)d_in[0];
    const float* w1 = (const float*)d_in[1];
    const float* b1 = (const float*)d_in[2];
    const float* wp = (const float*)d_in[3];
    const float* bp = (const float*)d_in[4];
    const float* W  = (const float*)d_in[5];
    float* out = (float*)d_out;
    float* ws = (float*)d_ws;

    float* u_t    = ws;                  // 786432
    float* c_t    = ws + 786432;         // 6291456 (B2 im2col reuses this region pre-routing)
    float* blog   = ws + 7077888;        // 6291456
    float* v      = ws + 13369344;       // 131072
    float* h1     = ws + 13500416;       // 479232 (region reused by s_part)
    float* s_part = ws + 13500416;       // 1572864
    float* B2     = c_t;                 // 884736 floats, dead before softmax writes c_t

    conv1_kernel<<<1872, 256, 0, stream>>>(x, w1, b1, h1);
    im2col_kernel<<<432, 256, 0, stream>>>(h1, B2);
    pc_gemm_kernel<<<dim3(192, 4), 256, 0, stream>>>(wp, bp, B2, u_t);

    // iteration 0: c uniform (1/64 folded into squash scale)
    spass_kernel<true><<<dim3(64, 12), 256, 0, stream>>>(W, u_t, nullptr, s_part);
    squashv_kernel<<<512, 256, 0, stream>>>(s_part, v, 1.f / 64.f);
    bpass_kernel<false><<<dim3(64, 24), 256, 0, stream>>>(W, u_t, v, blog);

    // iteration 1
    softmax_kernel<<<768, 128, 0, stream>>>(blog, c_t);
    spass_kernel<false><<<dim3(64, 12), 256, 0, stream>>>(W, u_t, c_t, s_part);
    squashv_kernel<<<512, 256, 0, stream>>>(s_part, v, 1.f);
    bpass_kernel<true><<<dim3(64, 24), 256, 0, stream>>>(W, u_t, v, blog);

    // final
    softmax_kernel<<<768, 128, 0, stream>>>(blog, c_t);
    spass_kernel<false><<<dim3(64, 12), 256, 0, stream>>>(W, u_t, c_t, s_part);
    squashv_kernel<<<512, 256, 0, stream>>>(s_part, out, 1.f);
}